// Round 2
// baseline (1038.597 us; speedup 1.0000x reference)
//
#include <hip/hip_runtime.h>
#include <cstdint>
#include <cstddef>

// ---------------------------------------------------------------------------
// QLoRABigNet: 6 blocks x (linear, relu, linear, relu, linear) + LayerNorm.
// D=1024, BATCH=16384. 18 bf16 MFMA GEMMs, LoRA merged into dequantized W.
// R6 change: GEMM fragment ds_reads SOFTWARE-PIPELINED one phase ahead
// (m201's "4 or 8 reads/phase" signature). R5 consumed frags in the same
// phase -> LDS drain serialized with MFMA (25% MfmaUtil). Now:
//   quadrants (0,0),(0,1),(1,1),(1,0); b0 held whole tile (16 VGPR).
//   ph1: MM(a0,b0)  | read b1 (4)        | stage Bh0(kt+1)
//   ph2: MM(a0,b1)  | read a1 (8)        | stage Bh1(kt+1) | vmcnt(6)
//   ph3: MM(a1,b1)  | read a0'(kt+1) (8) | stage Ah0(kt+2) | vmcnt(4)
//   ph4: MM(a1,b0)  | post-MM read b0'(kt+1) (4) | stage Ah1(kt+2) | vmcnt(4)
// Staging halves REDEFINED to match frag halves (A-h0 = rows [0,64)u[128,192);
// B-h0 = 32-row stripes == [0,32) mod 64) so counted vmcnt covers exactly
// the rows each phase reads. Tail: kt=14 vmcnt 2/0; kt=15 no stages/waits.
// ---------------------------------------------------------------------------

typedef short  bf16x8 __attribute__((ext_vector_type(8)));   // 8 bf16 (4 VGPRs)
typedef float  f32x4  __attribute__((ext_vector_type(4)));

__device__ __forceinline__ unsigned short f2bf(float f) {
  unsigned int u = __builtin_bit_cast(unsigned int, f);
  u += 0x7FFFu + ((u >> 16) & 1u);
  return (unsigned short)(u >> 16);
}

__device__ __forceinline__ void async_copy16(void* lds, const void* g) {
  __builtin_amdgcn_global_load_lds(
      (const __attribute__((address_space(1))) void*)(uintptr_t)(g),
      (__attribute__((address_space(3))) void*)(unsigned int)(uintptr_t)(lds),
      16, 0, 0);
}

// ---------------------------------------------------------------------------
// Dequant (+ LoRA merge). 4 independent int4 loads per thread (16 elements).
// grid: (256, 18), block 256.
// ---------------------------------------------------------------------------
__global__ __launch_bounds__(256) void dequant_kernel(
    const int* __restrict__ wq, const float* __restrict__ wn,
    const float* __restrict__ lora_a, const float* __restrict__ lora_b,
    unsigned short* __restrict__ Wbf) {
  const int l   = blockIdx.y;
  const int t   = threadIdx.x;
  const int blk = blockIdx.x;
  const long base = (long)l * 1048576;
  const float s = 2.0f / 15.0f;

  int4  q[4];
  float nrm[4];
#pragma unroll
  for (int k = 0; k < 4; ++k) {
    const int i4 = blk * 1024 + k * 256 + t;
    q[k]   = *(const int4*)(wq + base + (long)i4 * 4);
    nrm[k] = wn[l * 65536 + (i4 >> 2)];
  }

  float v[4][4];
#pragma unroll
  for (int k = 0; k < 4; ++k) {
    v[k][0] = ((float)q[k].x * s - 1.0f) * nrm[k];
    v[k][1] = ((float)q[k].y * s - 1.0f) * nrm[k];
    v[k][2] = ((float)q[k].z * s - 1.0f) * nrm[k];
    v[k][3] = ((float)q[k].w * s - 1.0f) * nrm[k];
  }

  const int slot = (l == 0) ? 0 : (l == 6) ? 1 : (l == 12) ? 2 : -1;
  if (slot >= 0) {
    const float* A = lora_a + slot * 32768 + t * 4;
    const float* B = lora_b + slot * 32768 + blk * 128;
#pragma unroll 8
    for (int r = 0; r < 32; ++r) {
      const float4 a4 = *(const float4*)(A + r * 1024);
#pragma unroll
      for (int k = 0; k < 4; ++k) {
        const float br = B[k * 32 + r];
        v[k][0] = fmaf(br, a4.x, v[k][0]);
        v[k][1] = fmaf(br, a4.y, v[k][1]);
        v[k][2] = fmaf(br, a4.z, v[k][2]);
        v[k][3] = fmaf(br, a4.w, v[k][3]);
      }
    }
  }

#pragma unroll
  for (int k = 0; k < 4; ++k) {
    unsigned short u[4] = {f2bf(v[k][0]), f2bf(v[k][1]),
                           f2bf(v[k][2]), f2bf(v[k][3])};
    const long e0 = base + ((long)blk * 1024 + k * 256 + t) * 4;
    *(uint2*)(Wbf + e0) = *(uint2*)u;
  }
}

// ---------------------------------------------------------------------------
// fp32 -> bf16 for the initial x. grid 4096, block 256 (16 elems/thread).
// ---------------------------------------------------------------------------
__global__ __launch_bounds__(256) void cvt_bf16_kernel(
    const float* __restrict__ in, unsigned short* __restrict__ out) {
  const long b0 = (long)blockIdx.x * 4096 + threadIdx.x * 4;
  float4 v[4];
#pragma unroll
  for (int k = 0; k < 4; ++k) v[k] = *(const float4*)(in + b0 + k * 1024);
#pragma unroll
  for (int k = 0; k < 4; ++k) {
    unsigned short u[4] = {f2bf(v[k].x), f2bf(v[k].y), f2bf(v[k].z), f2bf(v[k].w)};
    *(ushort4*)(out + b0 + k * 1024) = *(ushort4*)u;
  }
}

// ---------------------------------------------------------------------------
// GEMM: out[m][n] = sum_k H[m][k] * W[n][k] + bias[n]
// M=16384, N=1024, K=1024. 256x256 tile, BK=64, 8 waves (2Mx4N), per-wave
// 128x64 output. Pipelined 4-phase/K-tile schedule (see header).
// LDS 128 KiB dynamic: buf0 A[0,32K) B[32K,64K); buf1 at +64K.
// Chunk swizzle (both sides): row r, 16B chunk c stored at chunk c^(r&7).
// XCD swizzle: block b -> s=(b&7)*32+b/8 (bijective, 256%8==0).
// MODE 0: relu, bf16 out. MODE 1: no relu, fp32 out.
// ---------------------------------------------------------------------------
template <int MODE>
__global__ __launch_bounds__(512, 2) void gemm8_kernel(
    const unsigned short* __restrict__ H,   // [16384][1024] bf16
    const unsigned short* __restrict__ W,   // [1024][1024] bf16 (layer slice)
    const float* __restrict__ bias,         // [1024]
    unsigned short* __restrict__ outb,      // MODE 0
    float* __restrict__ outf) {             // MODE 1
  extern __shared__ char smem[];

  const int tid = threadIdx.x;
  const int w   = tid >> 6;        // wave 0..7
  const int ln  = tid & 63;
  const int wm  = w >> 2;          // 0..1  (M half)
  const int wn  = w & 3;           // 0..3  (N quarter)

  const int b  = blockIdx.x;
  const int s  = (b & 7) * 32 + (b >> 3);
  const int m0 = (s >> 2) * 256;
  const int n0 = (s & 3) * 256;

  // staging invariants: thread covers row_base + (ln>>3), phys chunk ln&7,
  // stored global chunk gc = (ln&7) ^ (row&7); all row bases are mult of 8.
  const int gc = (ln & 7) ^ ((ln >> 3) & 7);
  // A stage call (F=half, J=block): rows J*128 + F*64 + w*8 + (ln>>3)
  const unsigned eA2 = (unsigned)(m0 + w * 8 + (ln >> 3)) * 1024u + gc * 8;
  const int wofsA = w * 1024;
  // B stage call: rows J*128 + (w>>2)*64 + F*32 + (w&3)*8 + (ln>>3)
  const unsigned eB2 =
      (unsigned)(n0 + (w >> 2) * 64 + (w & 3) * 8 + (ln >> 3)) * 1024u + gc * 8;
  const int wofsB = (w >> 2) * 8192 + (w & 3) * 1024;

  // fragment reads: row base + swizzled chunk (kk*4+quad)^(lrow&7)
  const int quad = ln >> 4;
  const int lrow = ln & 15;
  const int sw   = lrow & 7;
  const int c0   = ((quad)     ^ sw) * 16;
  const int c1   = ((quad + 4) ^ sw) * 16;
  const int aoff = (wm * 128 + lrow) * 128;
  const int boff = (wn * 64  + lrow) * 128;

#define STAGE_A(T_, D_, F_, J_)                                                \
  async_copy16(smem + (D_) * 65536 + (J_) * 16384 + (F_) * 8192 + wofsA,       \
               H + eA2 + (unsigned)((T_) * 64 + ((J_) * 128 + (F_) * 64) * 1024))
#define STAGE_B(T_, D_, F_, J_)                                                \
  async_copy16(smem + (D_) * 65536 + 32768 + (J_) * 16384 + (F_) * 4096 + wofsB,\
               W + eB2 + (unsigned)((T_) * 64 + ((J_) * 128 + (F_) * 32) * 1024))
#define VMCNT(N_) asm volatile("s_waitcnt vmcnt(" #N_ ")" ::: "memory")
#define MM16(AV, BV, I0, J0)                                                   \
  {                                                                            \
    _Pragma("unroll") for (int i_ = 0; i_ < 4; ++i_) {                         \
      _Pragma("unroll") for (int j_ = 0; j_ < 2; ++j_) {                       \
        acc[(I0) + i_][(J0) + j_] = __builtin_amdgcn_mfma_f32_16x16x32_bf16(   \
            AV[i_][0], BV[j_][0], acc[(I0) + i_][(J0) + j_], 0, 0, 0);         \
        acc[(I0) + i_][(J0) + j_] = __builtin_amdgcn_mfma_f32_16x16x32_bf16(   \
            AV[i_][1], BV[j_][1], acc[(I0) + i_][(J0) + j_], 0, 0, 0);         \
      }                                                                        \
    }                                                                          \
  }
#define LDSUB4(DST, BASE, OFF)                                                 \
  {                                                                            \
    _Pragma("unroll") for (int i_ = 0; i_ < 4; ++i_) {                         \
      DST[i_][0] = *(const bf16x8*)((BASE) + (OFF) + i_ * 2048 + c0);          \
      DST[i_][1] = *(const bf16x8*)((BASE) + (OFF) + i_ * 2048 + c1);          \
    }                                                                          \
  }
#define LDSUB2(DST, BASE, OFF)                                                 \
  {                                                                            \
    _Pragma("unroll") for (int j_ = 0; j_ < 2; ++j_) {                         \
      DST[j_][0] = *(const bf16x8*)((BASE) + (OFF) + j_ * 2048 + c0);          \
      DST[j_][1] = *(const bf16x8*)((BASE) + (OFF) + j_ * 2048 + c1);          \
    }                                                                          \
  }

  f32x4 acc[8][4];
#pragma unroll
  for (int i = 0; i < 8; ++i)
#pragma unroll
    for (int j = 0; j < 4; ++j) acc[i][j] = (f32x4){0.f, 0.f, 0.f, 0.f};

  // prologue: tile0 (A h0,h1; B h0,h1) -> buf0 [8 loads]; tile1 A -> buf1 [4].
  STAGE_A(0, 0, 0, 0); STAGE_A(0, 0, 0, 1);
  STAGE_A(0, 0, 1, 0); STAGE_A(0, 0, 1, 1);
  STAGE_B(0, 0, 0, 0); STAGE_B(0, 0, 0, 1);
  STAGE_B(0, 0, 1, 0); STAGE_B(0, 0, 1, 1);
  asm volatile("" ::: "memory");
  STAGE_A(1, 1, 0, 0); STAGE_A(1, 1, 0, 1);
  STAGE_A(1, 1, 1, 0); STAGE_A(1, 1, 1, 1);
  VMCNT(4);                                   // tile0 landed; A(1) in flight
  __builtin_amdgcn_s_barrier();

  bf16x8 aX[4][2], aY[4][2], b0f[2][2], b1f[2][2];
  // preload frags for ph1 of tile 0 (consumed via compiler lgkm dep)
  LDSUB4(aX, smem, aoff);                     // a0(0)
  LDSUB2(b0f, smem + 32768, boff);            // b0(0)

  for (int kt = 0; kt < 16; ++kt) {
    const int BUF = kt & 1;
    const int nb  = BUF ^ 1;
    const char* At = smem + BUF * 65536;
    const char* Ao = smem + nb  * 65536;
    const char* Bt = At + 32768;
    const char* Bo = Ao + 32768;
    const bool ib = (kt < 15);
    const bool ia = (kt < 14);

    // ---- ph1: MM(a0,b0) | read b1(cur) | stage Bh0(kt+1) ------------------
    LDSUB2(b1f, Bt, boff + 4096);
    if (ib) { STAGE_B(kt + 1, nb, 0, 0); STAGE_B(kt + 1, nb, 0, 1); }
    __builtin_amdgcn_s_barrier();
    __builtin_amdgcn_s_setprio(1);
    MM16(aX, b0f, 0, 0);
    __builtin_amdgcn_s_setprio(0);
    __builtin_amdgcn_s_barrier();

    // ---- ph2: MM(a0,b1) | read a1(cur) | stage Bh1(kt+1) | vmcnt(6) -------
    LDSUB4(aY, At, aoff + 8192);
    if (ib) { STAGE_B(kt + 1, nb, 1, 0); STAGE_B(kt + 1, nb, 1, 1); }
    if (ib) VMCNT(6);                         // forces Ah0(kt+1)
    __builtin_amdgcn_s_barrier();
    __builtin_amdgcn_s_setprio(1);
    MM16(aX, b1f, 0, 2);
    __builtin_amdgcn_s_setprio(0);
    __builtin_amdgcn_s_barrier();

    // ---- ph3: MM(a1,b1) | read a0'(next) | stage Ah0(kt+2) | vmcnt(4) -----
    if (ib) LDSUB4(aX, Ao, aoff);             // a0(kt+1); aX free since ph2
    if (ia) { STAGE_A(kt + 2, BUF, 0, 0); STAGE_A(kt + 2, BUF, 0, 1); }
    if (ia) { VMCNT(4); }                     // forces Ah1(kt+1)+Bh0(kt+1)
    else if (kt == 14) { VMCNT(2); }          // forces Bh0(15)
    __builtin_amdgcn_s_barrier();
    __builtin_amdgcn_s_setprio(1);
    MM16(aY, b1f, 4, 2);
    __builtin_amdgcn_s_setprio(0);
    __builtin_amdgcn_s_barrier();

    // ---- ph4: MM(a1,b0) | stage Ah1(kt+2) | post-MM read b0' | vmcnt(4) ---
    if (ia) { STAGE_A(kt + 2, BUF, 1, 0); STAGE_A(kt + 2, BUF, 1, 1); }
    __builtin_amdgcn_s_barrier();
    __builtin_amdgcn_s_setprio(1);
    MM16(aY, b0f, 4, 0);
    __builtin_amdgcn_s_setprio(0);
    if (ib) LDSUB2(b0f, Bo, boff);            // b0(kt+1), after last b0 use
    if (ia) { VMCNT(4); }                     // forces Bh1(kt+1)
    else if (kt == 14) { VMCNT(0); }          // tail drain
    __builtin_amdgcn_s_barrier();
  }

#undef LDSUB2
#undef LDSUB4
#undef MM16
#undef VMCNT
#undef STAGE_B
#undef STAGE_A

  // epilogue: C/D layout col=lane&15, row=quad*4+reg
#pragma unroll
  for (int nt = 0; nt < 4; ++nt) {
    const int n = n0 + wn * 64 + nt * 16 + lrow;
    const float bs = bias[n];
#pragma unroll
    for (int mt = 0; mt < 8; ++mt) {
      const int mb = m0 + wm * 128 + mt * 16 + quad * 4;
      const f32x4 v = acc[mt][nt];
#pragma unroll
      for (int r = 0; r < 4; ++r) {
        float o = v[r] + bs;
        if (MODE == 0) {
          o = fmaxf(o, 0.0f);
          outb[(size_t)(mb + r) * 1024 + n] = f2bf(o);
        } else {
          outf[(size_t)(mb + r) * 1024 + n] = o;
        }
      }
    }
  }
}

// ---------------------------------------------------------------------------
// LayerNorm over rows of 1024. One WAVE per row (4 rows/block).
// grid 4096, block 256.
// ---------------------------------------------------------------------------
__global__ __launch_bounds__(256) void ln_kernel(
    const float* __restrict__ in, const float* __restrict__ lnw,
    const float* __restrict__ lnb, unsigned short* __restrict__ outb,
    float* __restrict__ outf, int wf32) {
  const int wv = threadIdx.x >> 6;
  const int ln = threadIdx.x & 63;
  const int row = blockIdx.x * 4 + wv;
  const float* p = in + (size_t)row * 1024;

  float4 v[4];
  float s = 0.f, q = 0.f;
#pragma unroll
  for (int c = 0; c < 4; ++c) {
    v[c] = *(const float4*)(p + c * 256 + ln * 4);
    s += v[c].x + v[c].y + v[c].z + v[c].w;
    q += v[c].x * v[c].x + v[c].y * v[c].y + v[c].z * v[c].z + v[c].w * v[c].w;
  }
#pragma unroll
  for (int off = 32; off; off >>= 1) {
    s += __shfl_xor(s, off);
    q += __shfl_xor(q, off);
  }
  const float mu  = s * (1.0f / 1024.0f);
  const float var = q * (1.0f / 1024.0f) - mu * mu;
  const float rs  = rsqrtf(var + 1e-5f);

#pragma unroll
  for (int c = 0; c < 4; ++c) {
    const int col = c * 256 + ln * 4;
    const float4 w4 = *(const float4*)(lnw + col);
    const float4 b4 = *(const float4*)(lnb + col);
    const float y0 = (v[c].x - mu) * rs * w4.x + b4.x;
    const float y1 = (v[c].y - mu) * rs * w4.y + b4.y;
    const float y2 = (v[c].z - mu) * rs * w4.z + b4.z;
    const float y3 = (v[c].w - mu) * rs * w4.w + b4.w;
    unsigned short u[4] = {f2bf(y0), f2bf(y1), f2bf(y2), f2bf(y3)};
    *(ushort4*)(outb + (size_t)row * 1024 + col) = *(ushort4*)u;
    if (wf32) {
      float4 y = make_float4(y0, y1, y2, y3);
      *(float4*)(outf + (size_t)row * 1024 + col) = y;
    }
  }
}

// ---------------------------------------------------------------------------
extern "C" void kernel_launch(void* const* d_in, const int* in_sizes, int n_in,
                              void* d_out, int out_size, void* d_ws, size_t ws_size,
                              hipStream_t stream) {
  const float* x    = (const float*)d_in[0];
  const int*   wq   = (const int*)d_in[1];
  const float* wn   = (const float*)d_in[2];
  const float* bias = (const float*)d_in[3];
  const float* la   = (const float*)d_in[4];
  const float* lb   = (const float*)d_in[5];
  const float* lnw  = (const float*)d_in[6];
  const float* lnb  = (const float*)d_in[7];
  float* out = (float*)d_out;

  char* ws = (char*)d_ws;
  unsigned short* Wbf = (unsigned short*)ws;                         // 37.75 MB
  unsigned short* hA  = (unsigned short*)(ws + 37748736);            // 32 MB
  unsigned short* hB  = (unsigned short*)(ws + 37748736 + 33554432); // 32 MB

  dequant_kernel<<<dim3(256, 18), 256, 0, stream>>>(wq, wn, la, lb, Wbf);
  cvt_bf16_kernel<<<4096, 256, 0, stream>>>(x, hA);

  for (int blk = 0; blk < 6; ++blk) {
    const int l = blk * 3;
    gemm8_kernel<0><<<256, 512, 131072, stream>>>(
        hA, Wbf + (size_t)l * 1048576, bias + l * 1024, hB, nullptr);
    gemm8_kernel<0><<<256, 512, 131072, stream>>>(
        hB, Wbf + (size_t)(l + 1) * 1048576, bias + (l + 1) * 1024, hA, nullptr);
    gemm8_kernel<1><<<256, 512, 131072, stream>>>(
        hA, Wbf + (size_t)(l + 2) * 1048576, bias + (l + 2) * 1024, nullptr, out);
    ln_kernel<<<4096, 256, 0, stream>>>(
        out, lnw + blk * 1024, lnb + blk * 1024, hA, out, blk == 5 ? 1 : 0);
  }
}

// Round 3
// 968.508 us; speedup vs baseline: 1.0724x; 1.0724x over previous
//
#include <hip/hip_runtime.h>
#include <cstdint>
#include <cstddef>

// ---------------------------------------------------------------------------
// QLoRABigNet: 6 blocks x (linear, relu, linear, relu, linear) + LayerNorm.
// R7: WITHIN-PROBE A/B. Blocks 0,2,4 -> proven 128^2 gemm_kernel (R0, 46us).
// Blocks 1,3,5 -> gemm8v2: R5's 256^2 4-phase schedule with sync slimmed to
// 4 barriers + 2 vmcnts per K-tile (was 8 + 3). Safety re-derived:
//  - stage(p) regions are disjoint from reads(p-1)..reads(p) regions; last
//    reader of every staged region retires >=1 barrier before the write.
//  - vmcnt(6)@ph2 pre-bar forces Ah0(kt+1) (read ph3); vmcnt(4)@ph4 post-MM
//    forces Bh0/Bh1(kt+1) (read ph4-end / ph1-next). Tail kt=14: vmcnt(0).
// Single barrier per phase allows +-1-phase wave skew -> stage/ds of one
// wave overlaps MFMA of the other wave on the same SIMD (setprio arbitrates).
// ---------------------------------------------------------------------------

typedef short  bf16x8 __attribute__((ext_vector_type(8)));   // 8 bf16 (4 VGPRs)
typedef float  f32x4  __attribute__((ext_vector_type(4)));

__device__ __forceinline__ unsigned short f2bf(float f) {
  unsigned int u = __builtin_bit_cast(unsigned int, f);
  u += 0x7FFFu + ((u >> 16) & 1u);
  return (unsigned short)(u >> 16);
}

__device__ __forceinline__ void async_copy16(void* lds, const void* g) {
  __builtin_amdgcn_global_load_lds(
      (const __attribute__((address_space(1))) void*)(uintptr_t)(g),
      (__attribute__((address_space(3))) void*)(unsigned int)(uintptr_t)(lds),
      16, 0, 0);
}

// ---------------------------------------------------------------------------
// Dequant (+ LoRA merge). grid (256,18), block 256.
// ---------------------------------------------------------------------------
__global__ __launch_bounds__(256) void dequant_kernel(
    const int* __restrict__ wq, const float* __restrict__ wn,
    const float* __restrict__ lora_a, const float* __restrict__ lora_b,
    unsigned short* __restrict__ Wbf) {
  const int l   = blockIdx.y;
  const int t   = threadIdx.x;
  const int blk = blockIdx.x;
  const long base = (long)l * 1048576;
  const float s = 2.0f / 15.0f;

  int4  q[4];
  float nrm[4];
#pragma unroll
  for (int k = 0; k < 4; ++k) {
    const int i4 = blk * 1024 + k * 256 + t;
    q[k]   = *(const int4*)(wq + base + (long)i4 * 4);
    nrm[k] = wn[l * 65536 + (i4 >> 2)];
  }

  float v[4][4];
#pragma unroll
  for (int k = 0; k < 4; ++k) {
    v[k][0] = ((float)q[k].x * s - 1.0f) * nrm[k];
    v[k][1] = ((float)q[k].y * s - 1.0f) * nrm[k];
    v[k][2] = ((float)q[k].z * s - 1.0f) * nrm[k];
    v[k][3] = ((float)q[k].w * s - 1.0f) * nrm[k];
  }

  const int slot = (l == 0) ? 0 : (l == 6) ? 1 : (l == 12) ? 2 : -1;
  if (slot >= 0) {
    const float* A = lora_a + slot * 32768 + t * 4;
    const float* B = lora_b + slot * 32768 + blk * 128;
#pragma unroll 8
    for (int r = 0; r < 32; ++r) {
      const float4 a4 = *(const float4*)(A + r * 1024);
#pragma unroll
      for (int k = 0; k < 4; ++k) {
        const float br = B[k * 32 + r];
        v[k][0] = fmaf(br, a4.x, v[k][0]);
        v[k][1] = fmaf(br, a4.y, v[k][1]);
        v[k][2] = fmaf(br, a4.z, v[k][2]);
        v[k][3] = fmaf(br, a4.w, v[k][3]);
      }
    }
  }

#pragma unroll
  for (int k = 0; k < 4; ++k) {
    unsigned short u[4] = {f2bf(v[k][0]), f2bf(v[k][1]),
                           f2bf(v[k][2]), f2bf(v[k][3])};
    const long e0 = base + ((long)blk * 1024 + k * 256 + t) * 4;
    *(uint2*)(Wbf + e0) = *(uint2*)u;
  }
}

// ---------------------------------------------------------------------------
// fp32 -> bf16 for the initial x. grid 4096, block 256.
// ---------------------------------------------------------------------------
__global__ __launch_bounds__(256) void cvt_bf16_kernel(
    const float* __restrict__ in, unsigned short* __restrict__ out) {
  const long b0 = (long)blockIdx.x * 4096 + threadIdx.x * 4;
  float4 v[4];
#pragma unroll
  for (int k = 0; k < 4; ++k) v[k] = *(const float4*)(in + b0 + k * 1024);
#pragma unroll
  for (int k = 0; k < 4; ++k) {
    unsigned short u[4] = {f2bf(v[k].x), f2bf(v[k].y), f2bf(v[k].z), f2bf(v[k].w)};
    *(ushort4*)(out + b0 + k * 1024) = *(ushort4*)u;
  }
}

// ---------------------------------------------------------------------------
// VARIANT A (proven R0): 128x128 tile, BK=64, 4 waves, 4 blocks/CU.
// grid 1024, block 256.
// ---------------------------------------------------------------------------
template <int MODE>
__global__ __launch_bounds__(256, 4) void gemm_kernel(
    const unsigned short* __restrict__ H,
    const unsigned short* __restrict__ W,
    const float* __restrict__ bias,
    unsigned short* __restrict__ outb,
    float* __restrict__ outf) {
  constexpr int K = 1024;
  constexpr int NN = 1024;

  __shared__ uint4 ldsq[2048];              // 32 KiB
  char* base = (char*)ldsq;

  const int tid = threadIdx.x;
  const int w   = tid >> 6;
  const int ln  = tid & 63;
  const int b   = blockIdx.x;
  const int m0  = ((b & 7) * 16 + (b >> 6)) * 128;
  const int n0  = ((b >> 3) & 7) * 128;

  const int gc = (ln & 7) ^ (ln >> 3);
  const unsigned short* gA = H + (size_t)(m0 + w * 32 + (ln >> 3)) * K + gc * 8;
  const unsigned short* gB = W + (size_t)(n0 + w * 32 + (ln >> 3)) * K + gc * 8;
  char* ldsA = base + w * 4096;
  char* ldsB = base + 16384 + w * 4096;

  const int quad = ln >> 4;
  const int lrow = ln & 15;
  const int sw   = lrow & 7;
  const int c0   = ((quad)     ^ sw) * 16;
  const int c1   = ((quad + 4) ^ sw) * 16;
  const int wm   = (w >> 1) * 64;
  const int wn   = (w & 1) * 64;
  const char* fragA = base + (wm + lrow) * 128;
  const char* fragB = base + 16384 + (wn + lrow) * 128;

  f32x4 acc[4][4];
#pragma unroll
  for (int i = 0; i < 4; ++i)
#pragma unroll
    for (int j = 0; j < 4; ++j) acc[i][j] = (f32x4){0.f, 0.f, 0.f, 0.f};

  for (int kt = 0; kt < 16; ++kt) {
    const unsigned short* pA = gA + kt * 64;
    const unsigned short* pB = gB + kt * 64;
#pragma unroll
    for (int i = 0; i < 4; ++i) {
      async_copy16(ldsA + i * 1024, pA + (size_t)i * 8 * K);
      async_copy16(ldsB + i * 1024, pB + (size_t)i * 8 * K);
    }
    __syncthreads();
#pragma unroll
    for (int kk = 0; kk < 2; ++kk) {
      const int co = kk ? c1 : c0;
      bf16x8 af[4], bg[4];
#pragma unroll
      for (int mt = 0; mt < 4; ++mt)
        af[mt] = *(const bf16x8*)(fragA + mt * 2048 + co);
#pragma unroll
      for (int nt = 0; nt < 4; ++nt)
        bg[nt] = *(const bf16x8*)(fragB + nt * 2048 + co);
#pragma unroll
      for (int mt = 0; mt < 4; ++mt)
#pragma unroll
        for (int nt = 0; nt < 4; ++nt)
          acc[mt][nt] = __builtin_amdgcn_mfma_f32_16x16x32_bf16(
              af[mt], bg[nt], acc[mt][nt], 0, 0, 0);
    }
    __syncthreads();
  }

#pragma unroll
  for (int nt = 0; nt < 4; ++nt) {
    const int n = n0 + wn + nt * 16 + lrow;
    const float bs = bias[n];
#pragma unroll
    for (int mt = 0; mt < 4; ++mt) {
      const int mb = m0 + wm + mt * 16 + quad * 4;
      f32x4 v = acc[mt][nt];
#pragma unroll
      for (int r = 0; r < 4; ++r) {
        float o = v[r] + bs;
        if (MODE == 0) {
          o = fmaxf(o, 0.0f);
          outb[(size_t)(mb + r) * NN + n] = f2bf(o);
        } else {
          outf[(size_t)(mb + r) * NN + n] = o;
        }
      }
    }
  }
}

// ---------------------------------------------------------------------------
// VARIANT B (gemm8v2): 256x256, BK=64, 8 waves, slim sync (4 bar + 2 vmcnt
// per K-tile). grid 256, block 512, 128 KiB dynamic LDS.
// ---------------------------------------------------------------------------
template <int MODE>
__global__ __launch_bounds__(512, 2) void gemm8v2_kernel(
    const unsigned short* __restrict__ H,
    const unsigned short* __restrict__ W,
    const float* __restrict__ bias,
    unsigned short* __restrict__ outb,
    float* __restrict__ outf) {
  extern __shared__ char smem[];

  const int tid = threadIdx.x;
  const int w   = tid >> 6;
  const int ln  = tid & 63;
  const int wm  = w >> 2;
  const int wn  = w & 3;

  const int b  = blockIdx.x;
  const int s  = (b & 7) * 32 + (b >> 3);
  const int m0 = (s >> 2) * 256;
  const int n0 = (s & 3) * 256;

  const int gc = (ln & 7) ^ ((ln >> 3) & 7);
  const unsigned eA2 = (unsigned)(m0 + w * 8 + (ln >> 3)) * 1024u + gc * 8;
  const int wofsA = w * 1024;
  const unsigned eB2 =
      (unsigned)(n0 + (w >> 2) * 64 + (w & 3) * 8 + (ln >> 3)) * 1024u + gc * 8;
  const int wofsB = (w >> 2) * 8192 + (w & 3) * 1024;

  const int quad = ln >> 4;
  const int lrow = ln & 15;
  const int sw   = lrow & 7;
  const int c0   = ((quad)     ^ sw) * 16;
  const int c1   = ((quad + 4) ^ sw) * 16;
  const int aoff = (wm * 128 + lrow) * 128;
  const int boff = (wn * 64  + lrow) * 128;

#define STAGE_A(T_, D_, F_, J_)                                                \
  async_copy16(smem + (D_) * 65536 + (J_) * 16384 + (F_) * 8192 + wofsA,       \
               H + eA2 + (unsigned)((T_) * 64 + ((J_) * 128 + (F_) * 64) * 1024))
#define STAGE_B(T_, D_, F_, J_)                                                \
  async_copy16(smem + (D_) * 65536 + 32768 + (J_) * 16384 + (F_) * 4096 + wofsB,\
               W + eB2 + (unsigned)((T_) * 64 + ((J_) * 128 + (F_) * 32) * 1024))
#define VMCNT(N_) asm volatile("s_waitcnt vmcnt(" #N_ ")" ::: "memory")
#define LGKM0()   asm volatile("s_waitcnt lgkmcnt(0)" ::: "memory")
#define MM16(AV, BV, I0, J0)                                                   \
  {                                                                            \
    _Pragma("unroll") for (int i_ = 0; i_ < 4; ++i_) {                         \
      _Pragma("unroll") for (int j_ = 0; j_ < 2; ++j_) {                       \
        acc[(I0) + i_][(J0) + j_] = __builtin_amdgcn_mfma_f32_16x16x32_bf16(   \
            AV[i_][0], BV[j_][0], acc[(I0) + i_][(J0) + j_], 0, 0, 0);         \
        acc[(I0) + i_][(J0) + j_] = __builtin_amdgcn_mfma_f32_16x16x32_bf16(   \
            AV[i_][1], BV[j_][1], acc[(I0) + i_][(J0) + j_], 0, 0, 0);         \
      }                                                                        \
    }                                                                          \
  }
#define LDSUB4(DST, BASE, OFF)                                                 \
  {                                                                            \
    _Pragma("unroll") for (int i_ = 0; i_ < 4; ++i_) {                         \
      DST[i_][0] = *(const bf16x8*)((BASE) + (OFF) + i_ * 2048 + c0);          \
      DST[i_][1] = *(const bf16x8*)((BASE) + (OFF) + i_ * 2048 + c1);          \
    }                                                                          \
  }
#define LDSUB2(DST, BASE, OFF)                                                 \
  {                                                                            \
    _Pragma("unroll") for (int j_ = 0; j_ < 2; ++j_) {                         \
      DST[j_][0] = *(const bf16x8*)((BASE) + (OFF) + j_ * 2048 + c0);          \
      DST[j_][1] = *(const bf16x8*)((BASE) + (OFF) + j_ * 2048 + c1);          \
    }                                                                          \
  }

  f32x4 acc[8][4];
#pragma unroll
  for (int i = 0; i < 8; ++i)
#pragma unroll
    for (int j = 0; j < 4; ++j) acc[i][j] = (f32x4){0.f, 0.f, 0.f, 0.f};

  // prologue: tile0 (8 loads) -> buf0; tile1 A (4 loads) -> buf1.
  STAGE_A(0, 0, 0, 0); STAGE_A(0, 0, 0, 1);
  STAGE_A(0, 0, 1, 0); STAGE_A(0, 0, 1, 1);
  STAGE_B(0, 0, 0, 0); STAGE_B(0, 0, 0, 1);
  STAGE_B(0, 0, 1, 0); STAGE_B(0, 0, 1, 1);
  asm volatile("" ::: "memory");
  STAGE_A(1, 1, 0, 0); STAGE_A(1, 1, 0, 1);
  STAGE_A(1, 1, 1, 0); STAGE_A(1, 1, 1, 1);
  VMCNT(4);                                   // tile0 landed; A(1)x4 in flight
  __builtin_amdgcn_s_barrier();

  bf16x8 aX[4][2], aY[4][2], b0f[2][2], b1f[2][2];
  LDSUB4(aX, smem, aoff);                     // a0(0)
  LDSUB2(b0f, smem + 32768, boff);            // b0(0)

#pragma unroll 2
  for (int kt = 0; kt < 16; ++kt) {
    const int BUF = kt & 1;
    const int nb  = BUF ^ 1;
    const char* At = smem + BUF * 65536;
    const char* Ao = smem + nb  * 65536;
    const char* Bt = At + 32768;
    const char* Bo = Ao + 32768;
    const bool ib = (kt < 15);
    const bool ia = (kt < 14);

    // ph1: MM(a0,b0) | read b1(cur) | stage Bh0(kt+1)
    LDSUB2(b1f, Bt, boff + 4096);
    if (ib) { STAGE_B(kt + 1, nb, 0, 0); STAGE_B(kt + 1, nb, 0, 1); }
    __builtin_amdgcn_s_barrier();
    LGKM0();
    __builtin_amdgcn_s_setprio(1);
    MM16(aX, b0f, 0, 0);
    __builtin_amdgcn_s_setprio(0);

    // ph2: MM(a0,b1) | read a1(cur) | stage Bh1(kt+1) | vmcnt(6) pre-bar
    LDSUB4(aY, At, aoff + 8192);
    if (ib) { STAGE_B(kt + 1, nb, 1, 0); STAGE_B(kt + 1, nb, 1, 1); }
    if (ib) VMCNT(6);                         // forces Ah0(kt+1) landed
    __builtin_amdgcn_s_barrier();
    LGKM0();
    __builtin_amdgcn_s_setprio(1);
    MM16(aX, b1f, 0, 2);
    __builtin_amdgcn_s_setprio(0);

    // ph3: MM(a1,b1) | read a0'(kt+1) | stage Ah0(kt+2)
    if (ib) LDSUB4(aX, Ao, aoff);
    if (ia) { STAGE_A(kt + 2, BUF, 0, 0); STAGE_A(kt + 2, BUF, 0, 1); }
    __builtin_amdgcn_s_barrier();
    LGKM0();
    __builtin_amdgcn_s_setprio(1);
    MM16(aY, b1f, 4, 2);
    __builtin_amdgcn_s_setprio(0);

    // ph4: MM(a1,b0) | stage Ah1(kt+2) | vmcnt(4) | read b0'(kt+1)
    if (ia) { STAGE_A(kt + 2, BUF, 1, 0); STAGE_A(kt + 2, BUF, 1, 1); }
    __builtin_amdgcn_s_barrier();
    LGKM0();
    __builtin_amdgcn_s_setprio(1);
    MM16(aY, b0f, 4, 0);
    __builtin_amdgcn_s_setprio(0);
    if (ia)            { VMCNT(4); }          // forces B(kt+1) landed
    else if (kt == 14) { VMCNT(0); }          // tail drain
    if (ib) LDSUB2(b0f, Bo, boff);            // b0(kt+1)
    __builtin_amdgcn_s_barrier();
  }

#undef LDSUB2
#undef LDSUB4
#undef MM16
#undef LGKM0
#undef VMCNT
#undef STAGE_B
#undef STAGE_A

#pragma unroll
  for (int nt = 0; nt < 4; ++nt) {
    const int n = n0 + wn * 64 + nt * 16 + lrow;
    const float bs = bias[n];
#pragma unroll
    for (int mt = 0; mt < 8; ++mt) {
      const int mb = m0 + wm * 128 + mt * 16 + quad * 4;
      const f32x4 v = acc[mt][nt];
#pragma unroll
      for (int r = 0; r < 4; ++r) {
        float o = v[r] + bs;
        if (MODE == 0) {
          o = fmaxf(o, 0.0f);
          outb[(size_t)(mb + r) * 1024 + n] = f2bf(o);
        } else {
          outf[(size_t)(mb + r) * 1024 + n] = o;
        }
      }
    }
  }
}

// ---------------------------------------------------------------------------
// LayerNorm over rows of 1024. One WAVE per row. grid 4096, block 256.
// ---------------------------------------------------------------------------
__global__ __launch_bounds__(256) void ln_kernel(
    const float* __restrict__ in, const float* __restrict__ lnw,
    const float* __restrict__ lnb, unsigned short* __restrict__ outb,
    float* __restrict__ outf, int wf32) {
  const int wv = threadIdx.x >> 6;
  const int ln = threadIdx.x & 63;
  const int row = blockIdx.x * 4 + wv;
  const float* p = in + (size_t)row * 1024;

  float4 v[4];
  float s = 0.f, q = 0.f;
#pragma unroll
  for (int c = 0; c < 4; ++c) {
    v[c] = *(const float4*)(p + c * 256 + ln * 4);
    s += v[c].x + v[c].y + v[c].z + v[c].w;
    q += v[c].x * v[c].x + v[c].y * v[c].y + v[c].z * v[c].z + v[c].w * v[c].w;
  }
#pragma unroll
  for (int off = 32; off; off >>= 1) {
    s += __shfl_xor(s, off);
    q += __shfl_xor(q, off);
  }
  const float mu  = s * (1.0f / 1024.0f);
  const float var = q * (1.0f / 1024.0f) - mu * mu;
  const float rs  = rsqrtf(var + 1e-5f);

#pragma unroll
  for (int c = 0; c < 4; ++c) {
    const int col = c * 256 + ln * 4;
    const float4 w4 = *(const float4*)(lnw + col);
    const float4 b4 = *(const float4*)(lnb + col);
    const float y0 = (v[c].x - mu) * rs * w4.x + b4.x;
    const float y1 = (v[c].y - mu) * rs * w4.y + b4.y;
    const float y2 = (v[c].z - mu) * rs * w4.z + b4.z;
    const float y3 = (v[c].w - mu) * rs * w4.w + b4.w;
    unsigned short u[4] = {f2bf(y0), f2bf(y1), f2bf(y2), f2bf(y3)};
    *(ushort4*)(outb + (size_t)row * 1024 + col) = *(ushort4*)u;
    if (wf32) {
      float4 y = make_float4(y0, y1, y2, y3);
      *(float4*)(outf + (size_t)row * 1024 + col) = y;
    }
  }
}

// ---------------------------------------------------------------------------
extern "C" void kernel_launch(void* const* d_in, const int* in_sizes, int n_in,
                              void* d_out, int out_size, void* d_ws, size_t ws_size,
                              hipStream_t stream) {
  const float* x    = (const float*)d_in[0];
  const int*   wq   = (const int*)d_in[1];
  const float* wn   = (const float*)d_in[2];
  const float* bias = (const float*)d_in[3];
  const float* la   = (const float*)d_in[4];
  const float* lb   = (const float*)d_in[5];
  const float* lnw  = (const float*)d_in[6];
  const float* lnb  = (const float*)d_in[7];
  float* out = (float*)d_out;

  char* ws = (char*)d_ws;
  unsigned short* Wbf = (unsigned short*)ws;                         // 37.75 MB
  unsigned short* hA  = (unsigned short*)(ws + 37748736);            // 32 MB
  unsigned short* hB  = (unsigned short*)(ws + 37748736 + 33554432); // 32 MB

  dequant_kernel<<<dim3(256, 18), 256, 0, stream>>>(wq, wn, la, lb, Wbf);
  cvt_bf16_kernel<<<4096, 256, 0, stream>>>(x, hA);

  for (int blk = 0; blk < 6; ++blk) {
    const int l = blk * 3;
    if ((blk & 1) == 0) {
      // VARIANT A: proven 128^2 kernel
      gemm_kernel<0><<<1024, 256, 0, stream>>>(
          hA, Wbf + (size_t)l * 1048576, bias + l * 1024, hB, nullptr);
      gemm_kernel<0><<<1024, 256, 0, stream>>>(
          hB, Wbf + (size_t)(l + 1) * 1048576, bias + (l + 1) * 1024, hA, nullptr);
      gemm_kernel<1><<<1024, 256, 0, stream>>>(
          hA, Wbf + (size_t)(l + 2) * 1048576, bias + (l + 2) * 1024, nullptr, out);
    } else {
      // VARIANT B: slim-sync 256^2
      gemm8v2_kernel<0><<<256, 512, 131072, stream>>>(
          hA, Wbf + (size_t)l * 1048576, bias + l * 1024, hB, nullptr);
      gemm8v2_kernel<0><<<256, 512, 131072, stream>>>(
          hB, Wbf + (size_t)(l + 1) * 1048576, bias + (l + 1) * 1024, hA, nullptr);
      gemm8v2_kernel<1><<<256, 512, 131072, stream>>>(
          hA, Wbf + (size_t)(l + 2) * 1048576, bias + (l + 2) * 1024, nullptr, out);
    }
    ln_kernel<<<4096, 256, 0, stream>>>(
        out, lnw + blk * 1024, lnb + blk * 1024, hA, out, blk == 5 ? 1 : 0);
  }
}

// Round 4
// 922.544 us; speedup vs baseline: 1.1258x; 1.0498x over previous
//
#include <hip/hip_runtime.h>
#include <cstdint>
#include <cstddef>

// ---------------------------------------------------------------------------
// QLoRABigNet: 6 blocks x (linear, relu, linear, relu, linear) + LayerNorm.
// D=1024, BATCH=16384. 18 bf16 MFMA GEMMs, LoRA merged into dequantized W.
//
// R8: GEMM scheduling experiments CLOSED. A/B verdict (R7): 256^2 8-wave
// slim-sync = 49us >= proven 128^2 4-blocks/CU = ~46us; implicit multi-block
// overlap (m114) beats hand pipelines at this shape. All GEMMs = variant A.
// R8 change: fp32 pre-LN intermediate eliminated for blocks 0-4:
//   GEMM3 MODE2 writes bf16 (67->33.5 MB), ln_bf16_kernel reads bf16
//   (67->33.5 MB). Block 5 keeps the exact fp32 path (MODE1 + fp32 LN) so
//   final-output precision is untouched; its dead hA bf16 write is skipped.
// Expected: -58us total. Added rounding is second-order (pre-LN h feeds a
// normalize whose output is bf16-quantized into hA anyway).
// ---------------------------------------------------------------------------

typedef short  bf16x8 __attribute__((ext_vector_type(8)));   // 8 bf16 (4 VGPRs)
typedef float  f32x4  __attribute__((ext_vector_type(4)));

__device__ __forceinline__ unsigned short f2bf(float f) {
  unsigned int u = __builtin_bit_cast(unsigned int, f);
  u += 0x7FFFu + ((u >> 16) & 1u);
  return (unsigned short)(u >> 16);
}

__device__ __forceinline__ void async_copy16(void* lds, const void* g) {
  __builtin_amdgcn_global_load_lds(
      (const __attribute__((address_space(1))) void*)(uintptr_t)(g),
      (__attribute__((address_space(3))) void*)(unsigned int)(uintptr_t)(lds),
      16, 0, 0);
}

// ---------------------------------------------------------------------------
// Dequant (+ LoRA merge). 4 independent int4 loads per thread (16 elements).
// grid (256, 18), block 256.
// ---------------------------------------------------------------------------
__global__ __launch_bounds__(256) void dequant_kernel(
    const int* __restrict__ wq, const float* __restrict__ wn,
    const float* __restrict__ lora_a, const float* __restrict__ lora_b,
    unsigned short* __restrict__ Wbf) {
  const int l   = blockIdx.y;
  const int t   = threadIdx.x;
  const int blk = blockIdx.x;
  const long base = (long)l * 1048576;
  const float s = 2.0f / 15.0f;

  int4  q[4];
  float nrm[4];
#pragma unroll
  for (int k = 0; k < 4; ++k) {
    const int i4 = blk * 1024 + k * 256 + t;
    q[k]   = *(const int4*)(wq + base + (long)i4 * 4);
    nrm[k] = wn[l * 65536 + (i4 >> 2)];
  }

  float v[4][4];
#pragma unroll
  for (int k = 0; k < 4; ++k) {
    v[k][0] = ((float)q[k].x * s - 1.0f) * nrm[k];
    v[k][1] = ((float)q[k].y * s - 1.0f) * nrm[k];
    v[k][2] = ((float)q[k].z * s - 1.0f) * nrm[k];
    v[k][3] = ((float)q[k].w * s - 1.0f) * nrm[k];
  }

  const int slot = (l == 0) ? 0 : (l == 6) ? 1 : (l == 12) ? 2 : -1;
  if (slot >= 0) {
    const float* A = lora_a + slot * 32768 + t * 4;
    const float* B = lora_b + slot * 32768 + blk * 128;
#pragma unroll 8
    for (int r = 0; r < 32; ++r) {
      const float4 a4 = *(const float4*)(A + r * 1024);
#pragma unroll
      for (int k = 0; k < 4; ++k) {
        const float br = B[k * 32 + r];
        v[k][0] = fmaf(br, a4.x, v[k][0]);
        v[k][1] = fmaf(br, a4.y, v[k][1]);
        v[k][2] = fmaf(br, a4.z, v[k][2]);
        v[k][3] = fmaf(br, a4.w, v[k][3]);
      }
    }
  }

#pragma unroll
  for (int k = 0; k < 4; ++k) {
    unsigned short u[4] = {f2bf(v[k][0]), f2bf(v[k][1]),
                           f2bf(v[k][2]), f2bf(v[k][3])};
    const long e0 = base + ((long)blk * 1024 + k * 256 + t) * 4;
    *(uint2*)(Wbf + e0) = *(uint2*)u;
  }
}

// ---------------------------------------------------------------------------
// fp32 -> bf16 for the initial x. grid 4096, block 256 (16 elems/thread).
// ---------------------------------------------------------------------------
__global__ __launch_bounds__(256) void cvt_bf16_kernel(
    const float* __restrict__ in, unsigned short* __restrict__ out) {
  const long b0 = (long)blockIdx.x * 4096 + threadIdx.x * 4;
  float4 v[4];
#pragma unroll
  for (int k = 0; k < 4; ++k) v[k] = *(const float4*)(in + b0 + k * 1024);
#pragma unroll
  for (int k = 0; k < 4; ++k) {
    unsigned short u[4] = {f2bf(v[k].x), f2bf(v[k].y), f2bf(v[k].z), f2bf(v[k].w)};
    *(ushort4*)(out + b0 + k * 1024) = *(ushort4*)u;
  }
}

// ---------------------------------------------------------------------------
// GEMM (proven R0 structure): out[m][n] = sum_k H[m][k]*W[n][k] + bias[n].
// 128x128 tile, BK=64, 4 waves, 4 blocks/CU, grid 1024, block 256.
// MODE 0: relu + bf16 out. MODE 1: fp32 out. MODE 2: bf16 out (no relu).
// ---------------------------------------------------------------------------
template <int MODE>
__global__ __launch_bounds__(256, 4) void gemm_kernel(
    const unsigned short* __restrict__ H,
    const unsigned short* __restrict__ W,
    const float* __restrict__ bias,
    unsigned short* __restrict__ outb,
    float* __restrict__ outf) {
  constexpr int K = 1024;
  constexpr int NN = 1024;

  __shared__ uint4 ldsq[2048];              // 32 KiB
  char* base = (char*)ldsq;

  const int tid = threadIdx.x;
  const int w   = tid >> 6;
  const int ln  = tid & 63;
  const int b   = blockIdx.x;
  const int m0  = ((b & 7) * 16 + (b >> 6)) * 128;
  const int n0  = ((b >> 3) & 7) * 128;

  const int gc = (ln & 7) ^ (ln >> 3);
  const unsigned short* gA = H + (size_t)(m0 + w * 32 + (ln >> 3)) * K + gc * 8;
  const unsigned short* gB = W + (size_t)(n0 + w * 32 + (ln >> 3)) * K + gc * 8;
  char* ldsA = base + w * 4096;
  char* ldsB = base + 16384 + w * 4096;

  const int quad = ln >> 4;
  const int lrow = ln & 15;
  const int sw   = lrow & 7;
  const int c0   = ((quad)     ^ sw) * 16;
  const int c1   = ((quad + 4) ^ sw) * 16;
  const int wm   = (w >> 1) * 64;
  const int wn   = (w & 1) * 64;
  const char* fragA = base + (wm + lrow) * 128;
  const char* fragB = base + 16384 + (wn + lrow) * 128;

  f32x4 acc[4][4];
#pragma unroll
  for (int i = 0; i < 4; ++i)
#pragma unroll
    for (int j = 0; j < 4; ++j) acc[i][j] = (f32x4){0.f, 0.f, 0.f, 0.f};

  for (int kt = 0; kt < 16; ++kt) {
    const unsigned short* pA = gA + kt * 64;
    const unsigned short* pB = gB + kt * 64;
#pragma unroll
    for (int i = 0; i < 4; ++i) {
      async_copy16(ldsA + i * 1024, pA + (size_t)i * 8 * K);
      async_copy16(ldsB + i * 1024, pB + (size_t)i * 8 * K);
    }
    __syncthreads();
#pragma unroll
    for (int kk = 0; kk < 2; ++kk) {
      const int co = kk ? c1 : c0;
      bf16x8 af[4], bg[4];
#pragma unroll
      for (int mt = 0; mt < 4; ++mt)
        af[mt] = *(const bf16x8*)(fragA + mt * 2048 + co);
#pragma unroll
      for (int nt = 0; nt < 4; ++nt)
        bg[nt] = *(const bf16x8*)(fragB + nt * 2048 + co);
#pragma unroll
      for (int mt = 0; mt < 4; ++mt)
#pragma unroll
        for (int nt = 0; nt < 4; ++nt)
          acc[mt][nt] = __builtin_amdgcn_mfma_f32_16x16x32_bf16(
              af[mt], bg[nt], acc[mt][nt], 0, 0, 0);
    }
    __syncthreads();
  }

#pragma unroll
  for (int nt = 0; nt < 4; ++nt) {
    const int n = n0 + wn + nt * 16 + lrow;
    const float bs = bias[n];
#pragma unroll
    for (int mt = 0; mt < 4; ++mt) {
      const int mb = m0 + wm + mt * 16 + quad * 4;
      f32x4 v = acc[mt][nt];
#pragma unroll
      for (int r = 0; r < 4; ++r) {
        float o = v[r] + bs;
        if (MODE == 0) o = fmaxf(o, 0.0f);
        if (MODE == 1) {
          outf[(size_t)(mb + r) * NN + n] = o;
        } else {
          outb[(size_t)(mb + r) * NN + n] = f2bf(o);
        }
      }
    }
  }
}

// ---------------------------------------------------------------------------
// LayerNorm (fp32 input; used for block 5 only). One WAVE per row.
// grid 4096, block 256. wbf: write bf16 hA; wf32: write fp32 out.
// ---------------------------------------------------------------------------
__global__ __launch_bounds__(256) void ln_kernel(
    const float* __restrict__ in, const float* __restrict__ lnw,
    const float* __restrict__ lnb, unsigned short* __restrict__ outb,
    float* __restrict__ outf, int wbf, int wf32) {
  const int wv = threadIdx.x >> 6;
  const int ln = threadIdx.x & 63;
  const int row = blockIdx.x * 4 + wv;
  const float* p = in + (size_t)row * 1024;

  float4 v[4];
  float s = 0.f, q = 0.f;
#pragma unroll
  for (int c = 0; c < 4; ++c) {
    v[c] = *(const float4*)(p + c * 256 + ln * 4);
    s += v[c].x + v[c].y + v[c].z + v[c].w;
    q += v[c].x * v[c].x + v[c].y * v[c].y + v[c].z * v[c].z + v[c].w * v[c].w;
  }
#pragma unroll
  for (int off = 32; off; off >>= 1) {
    s += __shfl_xor(s, off);
    q += __shfl_xor(q, off);
  }
  const float mu  = s * (1.0f / 1024.0f);
  const float var = q * (1.0f / 1024.0f) - mu * mu;
  const float rs  = rsqrtf(var + 1e-5f);

#pragma unroll
  for (int c = 0; c < 4; ++c) {
    const int col = c * 256 + ln * 4;
    const float4 w4 = *(const float4*)(lnw + col);
    const float4 b4 = *(const float4*)(lnb + col);
    const float y0 = (v[c].x - mu) * rs * w4.x + b4.x;
    const float y1 = (v[c].y - mu) * rs * w4.y + b4.y;
    const float y2 = (v[c].z - mu) * rs * w4.z + b4.z;
    const float y3 = (v[c].w - mu) * rs * w4.w + b4.w;
    if (wbf) {
      unsigned short u[4] = {f2bf(y0), f2bf(y1), f2bf(y2), f2bf(y3)};
      *(ushort4*)(outb + (size_t)row * 1024 + col) = *(ushort4*)u;
    }
    if (wf32) {
      float4 y = make_float4(y0, y1, y2, y3);
      *(float4*)(outf + (size_t)row * 1024 + col) = y;
    }
  }
}

// ---------------------------------------------------------------------------
// LayerNorm, bf16 input -> bf16 output (blocks 0-4). One WAVE per row;
// lane ln owns cols [ln*16, ln*16+16). grid 4096, block 256.
// ---------------------------------------------------------------------------
__global__ __launch_bounds__(256) void ln_bf16_kernel(
    const unsigned short* __restrict__ in, const float* __restrict__ lnw,
    const float* __restrict__ lnb, unsigned short* __restrict__ outb) {
  const int wv = threadIdx.x >> 6;
  const int ln = threadIdx.x & 63;
  const int row = blockIdx.x * 4 + wv;
  const unsigned short* p = in + (size_t)row * 1024 + ln * 16;

  const uint4 r0 = *(const uint4*)(p);
  const uint4 r1 = *(const uint4*)(p + 8);
  const unsigned ru[8] = {r0.x, r0.y, r0.z, r0.w, r1.x, r1.y, r1.z, r1.w};

  float f[16];
#pragma unroll
  for (int i = 0; i < 8; ++i) {
    f[2 * i]     = __builtin_bit_cast(float, ru[i] << 16);
    f[2 * i + 1] = __builtin_bit_cast(float, ru[i] & 0xffff0000u);
  }

  float s = 0.f, q = 0.f;
#pragma unroll
  for (int i = 0; i < 16; ++i) { s += f[i]; q += f[i] * f[i]; }
#pragma unroll
  for (int off = 32; off; off >>= 1) {
    s += __shfl_xor(s, off);
    q += __shfl_xor(q, off);
  }
  const float mu  = s * (1.0f / 1024.0f);
  const float var = q * (1.0f / 1024.0f) - mu * mu;
  const float rs  = rsqrtf(var + 1e-5f);

  const float* wp = lnw + ln * 16;
  const float* bp = lnb + ln * 16;
  unsigned o[8];
#pragma unroll
  for (int i = 0; i < 8; ++i) {
    const float y0 = (f[2 * i]     - mu) * rs * wp[2 * i]     + bp[2 * i];
    const float y1 = (f[2 * i + 1] - mu) * rs * wp[2 * i + 1] + bp[2 * i + 1];
    o[i] = (unsigned)f2bf(y0) | ((unsigned)f2bf(y1) << 16);
  }
  unsigned short* dst = outb + (size_t)row * 1024 + ln * 16;
  *(uint4*)(dst)     = make_uint4(o[0], o[1], o[2], o[3]);
  *(uint4*)(dst + 8) = make_uint4(o[4], o[5], o[6], o[7]);
}

// ---------------------------------------------------------------------------
extern "C" void kernel_launch(void* const* d_in, const int* in_sizes, int n_in,
                              void* d_out, int out_size, void* d_ws, size_t ws_size,
                              hipStream_t stream) {
  const float* x    = (const float*)d_in[0];
  const int*   wq   = (const int*)d_in[1];
  const float* wn   = (const float*)d_in[2];
  const float* bias = (const float*)d_in[3];
  const float* la   = (const float*)d_in[4];
  const float* lb   = (const float*)d_in[5];
  const float* lnw  = (const float*)d_in[6];
  const float* lnb  = (const float*)d_in[7];
  float* out = (float*)d_out;

  char* ws = (char*)d_ws;
  unsigned short* Wbf = (unsigned short*)ws;                         // 37.75 MB
  unsigned short* hA  = (unsigned short*)(ws + 37748736);            // 32 MB
  unsigned short* hB  = (unsigned short*)(ws + 37748736 + 33554432); // 32 MB

  dequant_kernel<<<dim3(256, 18), 256, 0, stream>>>(wq, wn, la, lb, Wbf);
  cvt_bf16_kernel<<<4096, 256, 0, stream>>>(x, hA);

  for (int blk = 0; blk < 6; ++blk) {
    const int l = blk * 3;
    gemm_kernel<0><<<1024, 256, 0, stream>>>(
        hA, Wbf + (size_t)l * 1048576, bias + l * 1024, hB, nullptr);
    gemm_kernel<0><<<1024, 256, 0, stream>>>(
        hB, Wbf + (size_t)(l + 1) * 1048576, bias + (l + 1) * 1024, hA, nullptr);
    if (blk < 5) {
      // bf16 pre-LN intermediate: GEMM3 -> hB (bf16), LN bf16 -> hA
      gemm_kernel<2><<<1024, 256, 0, stream>>>(
          hA, Wbf + (size_t)(l + 2) * 1048576, bias + (l + 2) * 1024, hB, nullptr);
      ln_bf16_kernel<<<4096, 256, 0, stream>>>(
          hB, lnw + blk * 1024, lnb + blk * 1024, hA);
    } else {
      // exact fp32 path for the final block
      gemm_kernel<1><<<1024, 256, 0, stream>>>(
          hA, Wbf + (size_t)(l + 2) * 1048576, bias + (l + 2) * 1024, nullptr, out);
      ln_kernel<<<4096, 256, 0, stream>>>(
          out, lnw + blk * 1024, lnb + blk * 1024, nullptr, out, 0, 1);
    }
  }
}